// Round 5
// baseline (110.750 us; speedup 1.0000x reference)
//
#include <hip/hip_runtime.h>

#define L 200
#define D 64
#define DA 128
#define INV_SCALE 0.088388347648318440550f  // 1/sqrt(128)

typedef float f32x4 __attribute__((ext_vector_type(4)));
typedef int   i32x4 __attribute__((ext_vector_type(4)));

// Single fused kernel: one wave per batch row.
//  - z = t @ Wq               (coalesced Wq reads, readlane t broadcast)
//  - q~ = (z @ Wk^T)/sqrt(128) (Wk staged in LDS [64][129] pad -> 2-way banks)
//  - stream hist: scores + relu(mask) + weighted accumulation, in registers,
//    depth-2 chunk pipeline (8 x 1KB nontemporal loads in flight)
//  - u = c @ Wv, out = u @ Wo + t  (coalesced, readlane broadcasts)
__global__ __launch_bounds__(256, 4) void attn_fused(
    const float* __restrict__ target, const float* __restrict__ hist,
    const int* __restrict__ mask,
    const float* __restrict__ Wq, const float* __restrict__ Wk,
    const float* __restrict__ Wv, const float* __restrict__ Wo,
    float* __restrict__ out)
{
    __shared__ float WkL[D * 129];     // 33024 B: Wk padded [64][129]
    __shared__ float smask[4][L];      // 3200 B: mask rows as float

    const int tid  = threadIdx.x;
    const int wave = tid >> 6, lane = tid & 63;
    const int b    = blockIdx.x * 4 + wave;
    const float* __restrict__ hb = hist + (size_t)b * (L * D);
    const int lr = lane >> 4;

    const float t = target[b * D + lane];

    // mask row -> LDS (values are 0/1)
    if (lane < 50) {
        i32x4 mv = *(const i32x4*)(mask + b * L + lane * 4);
        f32x4 mf = { (float)mv.x, (float)mv.y, (float)mv.z, (float)mv.w };
        *(f32x4*)&smask[wave][lane * 4] = mf;
    }

    // stage Wk -> LDS padded [64][129]; 8 float4 per thread, coalesced
    #pragma unroll
    for (int k = 0; k < 8; ++k) {
        int q4 = tid + k * 256;            // float4 index 0..2047
        int j  = q4 >> 5;                  // row 0..63
        int a  = (q4 & 31) << 2;           // col 0..124
        *(f32x4*)&WkL[j * 129 + a] = *(const f32x4*)(Wk + j * DA + a);
    }

    // z_a = sum_i t_i * Wq[i,a]; lane holds a=lane and a=lane+64
    float z0 = 0.f, z1 = 0.f;
    #pragma unroll
    for (int i = 0; i < D; ++i) {
        float ti = __shfl(t, i);
        z0 = fmaf(ti, Wq[i * DA + lane], z0);
        z1 = fmaf(ti, Wq[i * DA + 64 + lane], z1);
    }

    // issue first two hist chunks (HBM latency hides under q~ compute)
    const float* hp = hb + lane * 4;
    #define NT(off) __builtin_nontemporal_load((const f32x4*)(hp + (off)))
    f32x4 A0 = NT(0),    A1 = NT(256),  A2 = NT(512),  A3 = NT(768);
    f32x4 B0 = NT(1024), B1 = NT(1280), B2 = NT(1536), B3 = NT(1792);

    __syncthreads();   // WkL + smask visible

    // q~[lane] = INV_SCALE * sum_a z_a * Wk[lane, a]  (LDS row read, 2-way banks)
    float qt = 0.f;
    #pragma unroll
    for (int k = 0; k < 32; ++k) {
        f32x4 w = *(const f32x4*)&WkL[lane * 129 + (k << 2)];
        const int a = k << 2;
        float za0 = (a + 0 < 64) ? __shfl(z0, a + 0) : __shfl(z1, a - 64);
        float za1 = (a + 1 < 64) ? __shfl(z0, a + 1) : __shfl(z1, a - 63);
        float za2 = (a + 2 < 64) ? __shfl(z0, a + 2) : __shfl(z1, a - 62);
        float za3 = (a + 3 < 64) ? __shfl(z0, a + 3) : __shfl(z1, a - 61);
        qt = fmaf(za0, w.x, fmaf(za1, w.y, fmaf(za2, w.z, fmaf(za3, w.w, qt))));
    }
    qt *= INV_SCALE;

    // redistribute: lane needs q~[(lane&15)*4 + k]
    const int qb = (lane & 15) * 4;
    f32x4 q;
    q.x = __shfl(qt, qb + 0);
    q.y = __shfl(qt, qb + 1);
    q.z = __shfl(qt, qb + 2);
    q.w = __shfl(qt, qb + 3);

    f32x4 acc = { 0.f, 0.f, 0.f, 0.f };

    #define PROC(v, ROW0) {                                               \
        float s = v.x * q.x + v.y * q.y + v.z * q.z + v.w * q.w;          \
        s += __shfl_xor(s, 1);                                            \
        s += __shfl_xor(s, 2);                                            \
        s += __shfl_xor(s, 4);                                            \
        s += __shfl_xor(s, 8);                                            \
        float mf = smask[wave][(ROW0) + lr];                              \
        float aw = fmaxf(s * mf, 0.f);                                    \
        acc += v * aw; }

    // depth-2 pipeline over 16-row chunks; chunk c = rows 16c..16c+15
    #pragma unroll
    for (int cc = 0; cc < 10; ++cc) {
        f32x4 N0 = NT((cc + 2) * 1024);
        f32x4 N1 = NT((cc + 2) * 1024 + 256);
        f32x4 N2 = NT((cc + 2) * 1024 + 512);
        f32x4 N3 = NT((cc + 2) * 1024 + 768);
        PROC(A0, cc * 16 + 0)  PROC(A1, cc * 16 + 4)
        PROC(A2, cc * 16 + 8)  PROC(A3, cc * 16 + 12)
        A0 = B0; A1 = B1; A2 = B2; A3 = B3;
        B0 = N0; B1 = N1; B2 = N2; B3 = N3;
    }
    // A = chunk 10 (rows 160..175), B = chunk 11 (rows 176..191), tail 192..199
    f32x4 T0 = NT(12288), T1 = NT(12544);
    PROC(A0, 160) PROC(A1, 164) PROC(A2, 168) PROC(A3, 172)
    PROC(B0, 176) PROC(B1, 180) PROC(B2, 184) PROC(B3, 188)
    PROC(T0, 192) PROC(T1, 196)
    #undef PROC
    #undef NT

    // reduce acc across the 4 lanes sharing each column group
    acc.x += __shfl_xor(acc.x, 16); acc.x += __shfl_xor(acc.x, 32);
    acc.y += __shfl_xor(acc.y, 16); acc.y += __shfl_xor(acc.y, 32);
    acc.z += __shfl_xor(acc.z, 16); acc.z += __shfl_xor(acc.z, 32);
    acc.w += __shfl_xor(acc.w, 16); acc.w += __shfl_xor(acc.w, 32);

    // u_a = sum_i c_i * Wv[i,a]; c_i lives on lane (i>>2), component (i&3)
    float u0 = 0.f, u1 = 0.f;
    #pragma unroll
    for (int i = 0; i < D; ++i) {
        const int g = i >> 2, m4 = i & 3;
        float ci = (m4 == 0) ? __shfl(acc.x, g)
                 : (m4 == 1) ? __shfl(acc.y, g)
                 : (m4 == 2) ? __shfl(acc.z, g)
                 :             __shfl(acc.w, g);
        u0 = fmaf(ci, Wv[i * DA + lane], u0);
        u1 = fmaf(ci, Wv[i * DA + 64 + lane], u1);
    }

    // out[b][lane] = t + sum_a u_a * Wo[a, lane]
    float o = t;
    #pragma unroll
    for (int a = 0; a < DA; ++a) {
        float ua = (a < 64) ? __shfl(u0, a) : __shfl(u1, a - 64);
        o = fmaf(ua, Wo[a * D + lane], o);
    }
    out[b * D + lane] = o;
}

extern "C" void kernel_launch(void* const* d_in, const int* in_sizes, int n_in,
                              void* d_out, int out_size, void* d_ws, size_t ws_size,
                              hipStream_t stream) {
    const float* target = (const float*)d_in[0];
    const float* hist   = (const float*)d_in[1];
    const int*   mask   = (const int*)d_in[2];
    const float* Wq     = (const float*)d_in[3];
    const float* Wk     = (const float*)d_in[4];
    const float* Wv     = (const float*)d_in[5];
    const float* Wo     = (const float*)d_in[6];
    float* outp = (float*)d_out;

    attn_fused<<<8192 / 4, 256, 0, stream>>>(target, hist, mask,
                                             Wq, Wk, Wv, Wo, outp);
}